// Round 5
// baseline (152.275 us; speedup 1.0000x reference)
//
#include <hip/hip_runtime.h>
#include <hip/hip_cooperative_groups.h>
#include <hip/hip_bf16.h>
#include <math.h>

namespace cg = cooperative_groups;

#define COLORS 10
#define NB 32
#define H 128
#define W 128
#define NS 120          // 11*11 - 1 shifts
#define HW (H*W)

typedef unsigned int u32;
typedef unsigned long long u64;
typedef float f32x4 __attribute__((ext_vector_type(4)));
typedef short bf16x8 __attribute__((ext_vector_type(8)));

// ======================= fused cooperative kernel =======================
// Grid 512 = 32 b x 16 ytiles (8 rows each), 256 threads, 2 blocks/CU.
// Phase A: bitplane match partials for this block's 8 rows -> mpart[b][s][16]
// grid.sync()
// Phase B: reduce+softmax+A-fragments (redundant per block, cheap)
// Phase C: MFMA accumulation for this block's 8 rows, log, store.
#define TILE_R 8
#define DR 18            // TILE_R + 10 padded rows
#define NT 16            // ytiles

__global__ __launch_bounds__(256, 2) void fused_all(
    const int* __restrict__ demo_in, const int* __restrict__ demo_out,
    const int* __restrict__ query_in, const float* __restrict__ clw,
    const float* __restrict__ logit_scale,
    float* __restrict__ mpart, float* __restrict__ out)
{
    __shared__ u32 din_p[COLORS][DR][8];          // 5760 B, padded bitplanes
    __shared__ u32 dout_p[COLORS][TILE_R][4];     // 1280 B
    __shared__ __align__(16) int qs[DR][144];     // 10368 B, padded query rows
    __shared__ float sm[NS];                      // scores -> attention
    __shared__ unsigned short abf[128];           // bf16 att by lin; 121..127 = 0
    __shared__ float wexp[COLORS];

    int t   = threadIdx.x;
    int blk = blockIdx.x;
    int b   = blk >> 4;
    int yt  = blk & (NT - 1);
    int y0  = yt * TILE_R;
    int wave = t >> 6, lane = t & 63;

    if (t < COLORS) wexp[t] = __expf(clw[t]);

    // ---- stage padded query rows (independent; issue early) ----
    const int* q = query_in + b * HW;
    int vstage[11];
    #pragma unroll
    for (int i = 0; i < 11; i++) {
        int idx = t + i * 256;
        int r = idx / 144;
        int p = idx - r * 144;
        int gy = y0 - 5 + r;
        bool ok = (idx < DR * 144) & (gy >= 0) & (gy < H) & (p >= 5) & (p < 133);
        int cy = gy < 0 ? 0 : (gy > 127 ? 127 : gy);
        int cx = p < 5 ? 0 : (p > 132 ? 127 : p - 5);
        int ld = q[cy * W + cx];
        vstage[i] = ok ? ld : 0;
    }
    #pragma unroll
    for (int i = 0; i < 11; i++) {
        int idx = t + i * 256;
        if (idx < DR * 144) ((int*)qs)[idx] = vstage[i];
    }

    // ---- Phase A: bitplanes for demo rows of this window ----
    const int* di = demo_in  + b * HW;
    const int* dd = demo_out + b * HW;

    for (int r = wave; r < DR; r += 4) {
        int gy = y0 - 5 + r;
        bool ok = (gy >= 0 && gy < H);
        int v0 = 0, v1 = 0;
        if (ok) { v0 = di[gy * W + lane]; v1 = di[gy * W + 64 + lane]; }
        #pragma unroll
        for (int c = 0; c < COLORS; c++) {
            u64 h0 = __ballot(v0 == c);
            u64 h1 = __ballot(v1 == c);
            u64 P0, P1, P2;
            if (!ok) {
                P0 = (c == 0) ? ~0ull : 0ull;
                P1 = P0;
                P2 = (c == 0) ? 0x3FFull : 0ull;
            } else {
                u64 lm = (c == 0) ? 0x1Full  : 0ull;
                u64 rm = (c == 0) ? 0x3E0ull : 0ull;
                P0 = (h0 << 5) | lm;
                P1 = (h0 >> 59) | (h1 << 5);
                P2 = (h1 >> 59) | rm;
            }
            if (lane == 0) {
                u32* w = &din_p[c][r][0];
                w[0] = (u32)P0; w[1] = (u32)(P0 >> 32);
                w[2] = (u32)P1; w[3] = (u32)(P1 >> 32);
                w[4] = (u32)P2; w[5] = 0; w[6] = 0; w[7] = 0;
            }
        }
    }
    for (int r = wave; r < TILE_R; r += 4) {
        int gy = y0 + r;
        int v0 = dd[gy * W + lane], v1 = dd[gy * W + 64 + lane];
        #pragma unroll
        for (int c = 0; c < COLORS; c++) {
            u64 h0 = __ballot(v0 == c);
            u64 h1 = __ballot(v1 == c);
            if (lane == 0) {
                u32* w = &dout_p[c][r][0];
                w[0] = (u32)h0; w[1] = (u32)(h0 >> 32);
                w[2] = (u32)h1; w[3] = (u32)(h1 >> 32);
            }
        }
    }
    __syncthreads();

    // match partials: t = s*2 + half, half covers 4 rows
    if (t < 2 * NS) {
        int s = t >> 1, half = t & 1;
        int lin = s + (s >= 60);
        int dy = lin / 11 - 5, dx = lin % 11 - 5;
        int k = 5 - dx;
        float acc = 0.f;
        for (int c = 0; c < COLORS; c++) {
            int cnt = 0;
            #pragma unroll
            for (int yy = 0; yy < 4; yy++) {
                int y = half * 4 + yy;
                int r = y - dy + 5;                 // 0..17
                const u32* dr   = &din_p[c][r][0];
                const u32* orow = &dout_p[c][y][0];
                u32 s0 = __builtin_amdgcn_alignbit(dr[1], dr[0], k);
                u32 s1 = __builtin_amdgcn_alignbit(dr[2], dr[1], k);
                u32 s2 = __builtin_amdgcn_alignbit(dr[3], dr[2], k);
                u32 s3 = __builtin_amdgcn_alignbit(dr[4], dr[3], k);
                cnt += __popc(s0 & orow[0]) + __popc(s1 & orow[1])
                     + __popc(s2 & orow[2]) + __popc(s3 & orow[3]);
            }
            acc += wexp[c] * (float)cnt;
        }
        float o = __shfl_down(acc, 1, 64);
        if (!(t & 1)) mpart[(b * NS + s) * NT + yt] = acc + o;
    }

    __threadfence();
    cg::this_grid().sync();
    __threadfence();

    // ---- Phase B: strip reduction + softmax + attention table ----
    float scale = fminf(__expf(logit_scale[0]), 100.0f) * (1.0f / 128.0f);
    if (t < NS) {
        const float* mp = mpart + (b * NS + t) * NT;
        float a = 0.f;
        #pragma unroll
        for (int i = 0; i < NT / 4; i++) {
            float4 v = *reinterpret_cast<const float4*>(mp + i * 4);
            a += v.x + v.y + v.z + v.w;
        }
        sm[t] = a * scale;
    }
    __syncthreads();
    if (t < 64) {
        int l = t;
        float s0 = sm[l];
        float s1 = (l + 64 < NS) ? sm[l + 64] : -INFINITY;
        float m = fmaxf(s0, s1);
        for (int off = 32; off > 0; off >>= 1) m = fmaxf(m, __shfl_xor(m, off, 64));
        float e0 = __expf(s0 - m);
        float e1 = (l + 64 < NS) ? __expf(s1 - m) : 0.f;
        float sum = e0 + e1;
        for (int off = 32; off > 0; off >>= 1) sum += __shfl_xor(sum, off, 64);
        float inv = 1.0f / sum;
        sm[l] = e0 * inv;
        if (l + 64 < NS) sm[l + 64] = e1 * inv;
    }
    __syncthreads();
    if (t < 128) {
        unsigned short v = 0;
        if (t < 121 && t != 60) {
            int si = t - (t > 60);
            __hip_bfloat16 hb = __float2bfloat16(sm[si]);
            v = *reinterpret_cast<unsigned short*>(&hb);
        }
        abf[t] = v;
    }
    __syncthreads();

    // per-lane A fragments: A[m][k=(st,cc)] = att(dy=5-st, dx=m+5-cc)
    int mrow = lane & 15, g8 = (lane >> 4) * 8;
    uint4 afr[11];
    #pragma unroll
    for (int st = 0; st < 11; st++) {
        u32 wq[4];
        #pragma unroll
        for (int p = 0; p < 4; p++) {
            int j0 = mrow + 10 - (g8 + p * 2);   // dx+5 for hh=0
            int j1 = j0 - 1;                     // hh=1
            int i0 = (j0 >= 0 && j0 <= 10) ? (10 - st) * 11 + j0 : 121;
            int i1 = (j1 >= 0 && j1 <= 10) ? (10 - st) * 11 + j1 : 121;
            wq[p] = (u32)abf[i0] | ((u32)abf[i1] << 16);
        }
        afr[st] = make_uint4(wq[0], wq[1], wq[2], wq[3]);
    }

    // ---- Phase C: MFMA accumulation over this block's 8 rows ----
    int c = lane & 15, g = lane >> 4;
    int wv = wave;

    #pragma unroll
    for (int ti = 0; ti < 2; ti++) {
        int x0 = wv * 32 + ti * 16;

        uint4 bf[DR];
        #pragma unroll
        for (int r = 0; r < DR; r++) {
            uint4 qa = *reinterpret_cast<const uint4*>(&qs[r][x0 + 8 * g]);
            uint4 qb = *reinterpret_cast<const uint4*>(&qs[r][x0 + 8 * g + 4]);
            u32 b0 = ((int)qa.x == c ? 0x3F80u : 0u) | ((int)qa.y == c ? 0x3F800000u : 0u);
            u32 b1 = ((int)qa.z == c ? 0x3F80u : 0u) | ((int)qa.w == c ? 0x3F800000u : 0u);
            u32 b2 = ((int)qb.x == c ? 0x3F80u : 0u) | ((int)qb.y == c ? 0x3F800000u : 0u);
            u32 b3 = ((int)qb.z == c ? 0x3F80u : 0u) | ((int)qb.w == c ? 0x3F800000u : 0u);
            bf[r] = make_uint4(b0, b1, b2, b3);
        }

        f32x4 acc[TILE_R];
        #pragma unroll
        for (int j = 0; j < TILE_R; j++) acc[j] = (f32x4){0.f, 0.f, 0.f, 0.f};

        #pragma unroll
        for (int st = 0; st < 11; st++) {
            #pragma unroll
            for (int j = 0; j < TILE_R; j++) {
                union { uint4 u; bf16x8 v; } A, B;
                A.u = afr[st];
                B.u = bf[st + j];
                acc[j] = __builtin_amdgcn_mfma_f32_16x16x32_bf16(A.v, B.v, acc[j], 0, 0, 0);
            }
        }

        if (c < COLORS) {
            #pragma unroll
            for (int j = 0; j < TILE_R; j++) {
                float* ob = out + (((size_t)b * COLORS + c) * H + (y0 + j)) * W + x0 + 4 * g;
                float4 rr;
                rr.x = __logf(fmaxf(acc[j][0], 1e-6f));
                rr.y = __logf(fmaxf(acc[j][1], 1e-6f));
                rr.z = __logf(fmaxf(acc[j][2], 1e-6f));
                rr.w = __logf(fmaxf(acc[j][3], 1e-6f));
                *reinterpret_cast<float4*>(ob) = rr;
            }
        }
    }
}

// ===================== fallback: round-4 3-kernel path =====================
#define STRIPS 8
#define SH 16
#define DROWS 26
#define DINW 8

__global__ __launch_bounds__(256) void match_strip(
    const int* __restrict__ demo_in, const int* __restrict__ demo_out,
    const float* __restrict__ clw, float* __restrict__ mpart)
{
    __shared__ u32 din_p[COLORS][DROWS][DINW];
    __shared__ u32 dout_p[COLORS][SH][4];
    __shared__ float wexp[COLORS];
    __shared__ float pp[128];

    int t = threadIdx.x;
    int strip = blockIdx.x;
    int b = blockIdx.y;
    int wave = t >> 6, lane = t & 63;

    if (t < COLORS) wexp[t] = __expf(clw[t]);

    const int* di = demo_in  + b * HW;
    const int* dd = demo_out + b * HW;
    int y0 = strip * SH;

    for (int r = wave; r < DROWS; r += 4) {
        int gy = y0 - 5 + r;
        bool ok = (gy >= 0 && gy < H);
        int v0 = 0, v1 = 0;
        if (ok) { v0 = di[gy * W + lane]; v1 = di[gy * W + 64 + lane]; }
        #pragma unroll
        for (int c = 0; c < COLORS; c++) {
            u64 h0 = __ballot(v0 == c);
            u64 h1 = __ballot(v1 == c);
            u64 P0, P1, P2;
            if (!ok) {
                P0 = (c == 0) ? ~0ull : 0ull;
                P1 = P0;
                P2 = (c == 0) ? 0x3FFull : 0ull;
            } else {
                u64 lm = (c == 0) ? 0x1Full  : 0ull;
                u64 rm = (c == 0) ? 0x3E0ull : 0ull;
                P0 = (h0 << 5) | lm;
                P1 = (h0 >> 59) | (h1 << 5);
                P2 = (h1 >> 59) | rm;
            }
            if (lane == 0) {
                u32* w = &din_p[c][r][0];
                w[0] = (u32)P0; w[1] = (u32)(P0 >> 32);
                w[2] = (u32)P1; w[3] = (u32)(P1 >> 32);
                w[4] = (u32)P2; w[5] = 0; w[6] = 0; w[7] = 0;
            }
        }
    }
    for (int r = wave; r < SH; r += 4) {
        int gy = y0 + r;
        int v0 = dd[gy * W + lane], v1 = dd[gy * W + 64 + lane];
        #pragma unroll
        for (int c = 0; c < COLORS; c++) {
            u64 h0 = __ballot(v0 == c);
            u64 h1 = __ballot(v1 == c);
            if (lane == 0) {
                u32* w = &dout_p[c][r][0];
                w[0] = (u32)h0; w[1] = (u32)(h0 >> 32);
                w[2] = (u32)h1; w[3] = (u32)(h1 >> 32);
            }
        }
    }
    __syncthreads();

    int s  = t & 127;
    int yh = t >> 7;
    float acc = 0.f;
    if (s < NS) {
        int lin = s + (s >= 60);
        int dy = lin / 11 - 5, dx = lin % 11 - 5;
        int k = 5 - dx;
        for (int c = 0; c < COLORS; c++) {
            int cnt = 0;
            #pragma unroll
            for (int yy = 0; yy < 8; yy++) {
                int y = yh * 8 + yy;
                int r = y - dy + 5;
                const u32* dr   = &din_p[c][r][0];
                const u32* orow = &dout_p[c][y][0];
                u32 s0 = __builtin_amdgcn_alignbit(dr[1], dr[0], k);
                u32 s1 = __builtin_amdgcn_alignbit(dr[2], dr[1], k);
                u32 s2 = __builtin_amdgcn_alignbit(dr[3], dr[2], k);
                u32 s3 = __builtin_amdgcn_alignbit(dr[4], dr[3], k);
                cnt += __popc(s0 & orow[0]) + __popc(s1 & orow[1])
                     + __popc(s2 & orow[2]) + __popc(s3 & orow[3]);
            }
            acc += wexp[c] * (float)cnt;
        }
    }
    if (yh == 1) pp[s] = acc;
    __syncthreads();
    if (yh == 0 && s < NS)
        mpart[(b * NS + s) * STRIPS + strip] = acc + pp[s];
}

__global__ __launch_bounds__(256) void softmax_abuild(
    const float* __restrict__ mpart, const float* __restrict__ logit_scale,
    u32* __restrict__ Ag)
{
    __shared__ float sm[NS];
    __shared__ float sa[NS];
    int b = blockIdx.x;
    int t = threadIdx.x;
    float scale = fminf(__expf(logit_scale[0]), 100.0f) * (1.0f / 128.0f);

    if (t < NS) {
        const float* mp = mpart + (b * NS + t) * STRIPS;
        float a = 0;
        #pragma unroll
        for (int i = 0; i < STRIPS; i++) a += mp[i];
        sm[t] = a * scale;
    }
    __syncthreads();

    if (t < 64) {
        int l = t;
        float s0 = sm[l];
        float s1 = (l + 64 < NS) ? sm[l + 64] : -INFINITY;
        float m = fmaxf(s0, s1);
        for (int off = 32; off > 0; off >>= 1) m = fmaxf(m, __shfl_xor(m, off, 64));
        float e0 = __expf(s0 - m);
        float e1 = (l + 64 < NS) ? __expf(s1 - m) : 0.f;
        float sum = e0 + e1;
        for (int off = 32; off > 0; off >>= 1) sum += __shfl_xor(sum, off, 64);
        float inv = 1.0f / sum;
        sa[l] = e0 * inv;
        if (l + 64 < NS) sa[l + 64] = e1 * inv;
    }
    __syncthreads();

    int wv = t >> 6, lane = t & 63;
    int mrow = lane & 15, g8 = (lane >> 4) * 8;
    for (int st = wv; st < 11; st += 4) {
        int dy = 5 - st;
        u32 wq[4];
        #pragma unroll
        for (int p = 0; p < 4; p++) {
            u32 wvv = 0;
            #pragma unroll
            for (int hh = 0; hh < 2; hh++) {
                int cc = g8 + p * 2 + hh;
                int dx = mrow + 5 - cc;
                unsigned short hv = 0;
                if (dx >= -5 && dx <= 5 && !(dy == 0 && dx == 0)) {
                    int lin = (dy + 5) * 11 + (dx + 5);
                    int si = lin - (lin > 60);
                    __hip_bfloat16 hb = __float2bfloat16(sa[si]);
                    hv = *reinterpret_cast<unsigned short*>(&hb);
                }
                wvv |= ((u32)hv) << (16 * hh);
            }
            wq[p] = wvv;
        }
        *reinterpret_cast<uint4*>(Ag + ((size_t)(b * 11 + st) * 64 + lane) * 4) =
            make_uint4(wq[0], wq[1], wq[2], wq[3]);
    }
}

__global__ __launch_bounds__(256) void accum_mfma(
    const int* __restrict__ query_in, const u32* __restrict__ Ag,
    float* __restrict__ out)
{
    __shared__ __align__(16) int qs[14][144];
    int t = threadIdx.x;
    int y0 = blockIdx.x * 4;
    int b  = blockIdx.y;
    const int* q = query_in + b * HW;

    int vstage[8];
    #pragma unroll
    for (int i = 0; i < 8; i++) {
        int idx = t + i * 256;
        int r = idx / 144;
        int p = idx - r * 144;
        int gy = y0 - 5 + r;
        bool ok = (idx < 2016) & (gy >= 0) & (gy < H) & (p >= 5) & (p < 133);
        int cy = gy < 0 ? 0 : (gy > 127 ? 127 : gy);
        int cx = p < 5 ? 0 : (p > 132 ? 127 : p - 5);
        int ld = q[cy * W + cx];
        vstage[i] = ok ? ld : 0;
    }

    int lane = t & 63, wv = t >> 6;
    uint4 afr[11];
    #pragma unroll
    for (int st = 0; st < 11; st++)
        afr[st] = *reinterpret_cast<const uint4*>(
            Ag + ((size_t)(b * 11 + st) * 64 + lane) * 4);

    #pragma unroll
    for (int i = 0; i < 8; i++) {
        int idx = t + i * 256;
        if (idx < 2016) ((int*)qs)[idx] = vstage[i];
    }
    __syncthreads();

    int c = lane & 15, g = lane >> 4;

    #pragma unroll
    for (int ti = 0; ti < 2; ti++) {
        int x0 = wv * 32 + ti * 16;

        uint4 bf[14];
        #pragma unroll
        for (int r = 0; r < 14; r++) {
            uint4 qa = *reinterpret_cast<const uint4*>(&qs[r][x0 + 8 * g]);
            uint4 qb = *reinterpret_cast<const uint4*>(&qs[r][x0 + 8 * g + 4]);
            u32 b0 = ((int)qa.x == c ? 0x3F80u : 0u) | ((int)qa.y == c ? 0x3F800000u : 0u);
            u32 b1 = ((int)qa.z == c ? 0x3F80u : 0u) | ((int)qa.w == c ? 0x3F800000u : 0u);
            u32 b2 = ((int)qb.x == c ? 0x3F80u : 0u) | ((int)qb.y == c ? 0x3F800000u : 0u);
            u32 b3 = ((int)qb.z == c ? 0x3F80u : 0u) | ((int)qb.w == c ? 0x3F800000u : 0u);
            bf[r] = make_uint4(b0, b1, b2, b3);
        }

        f32x4 acc[4];
        #pragma unroll
        for (int j = 0; j < 4; j++) acc[j] = (f32x4){0.f, 0.f, 0.f, 0.f};

        #pragma unroll
        for (int st = 0; st < 11; st++) {
            #pragma unroll
            for (int j = 0; j < 4; j++) {
                union { uint4 u; bf16x8 v; } A, B;
                A.u = afr[st];
                B.u = bf[st + j];
                acc[j] = __builtin_amdgcn_mfma_f32_16x16x32_bf16(A.v, B.v, acc[j], 0, 0, 0);
            }
        }

        if (c < COLORS) {
            #pragma unroll
            for (int j = 0; j < 4; j++) {
                float* ob = out + (((size_t)b * COLORS + c) * H + (y0 + j)) * W + x0 + 4 * g;
                float4 rr;
                rr.x = __logf(fmaxf(acc[j][0], 1e-6f));
                rr.y = __logf(fmaxf(acc[j][1], 1e-6f));
                rr.z = __logf(fmaxf(acc[j][2], 1e-6f));
                rr.w = __logf(fmaxf(acc[j][3], 1e-6f));
                *reinterpret_cast<float4*>(ob) = rr;
            }
        }
    }
}

extern "C" void kernel_launch(void* const* d_in, const int* in_sizes, int n_in,
                              void* d_out, int out_size, void* d_ws, size_t ws_size,
                              hipStream_t stream) {
    const int*   demo_in     = (const int*)d_in[0];
    const int*   demo_out    = (const int*)d_in[1];
    const int*   query_in    = (const int*)d_in[2];
    const float* clw         = (const float*)d_in[3];
    const float* logit_scale = (const float*)d_in[4];
    float* out = (float*)d_out;

    // fused path: mpart[b][s][16]
    size_t fused_need = (size_t)NB * NS * NT * sizeof(float);   // 245760
    bool done = false;
    if (ws_size >= fused_need) {
        float* mp = (float*)d_ws;
        void* args[7] = { (void*)&demo_in, (void*)&demo_out, (void*)&query_in,
                          (void*)&clw, (void*)&logit_scale, (void*)&mp, (void*)&out };
        hipError_t e = hipLaunchCooperativeKernel((const void*)fused_all,
                                                  dim3(NB * NT), dim3(256),
                                                  args, 0, stream);
        done = (e == hipSuccess);
    }
    if (done) return;

    // fallback: round-4 3-kernel pipeline
    size_t mpart_sz = (size_t)NB * NS * STRIPS * 4;
    size_t att_off  = mpart_sz;
    size_t ag_off   = att_off + (size_t)NB * NS * 4;
    size_t needed   = ag_off + (size_t)NB * 11 * 64 * 16;

    if (ws_size >= needed) {
        float* mpart = (float*)d_ws;
        u32*   Ag    = (u32*)((char*)d_ws + ag_off);
        match_strip<<<dim3(STRIPS, NB), 256, 0, stream>>>(demo_in, demo_out, clw, mpart);
        softmax_abuild<<<NB, 256, 0, stream>>>(mpart, logit_scale, Ag);
        accum_mfma<<<dim3(H / 4, NB), 256, 0, stream>>>(query_in, Ag, out);
    }
}

// Round 6
// 35.347 us; speedup vs baseline: 4.3080x; 4.3080x over previous
//
#include <hip/hip_runtime.h>
#include <hip/hip_bf16.h>
#include <math.h>

#define COLORS 10
#define NB 32
#define H 128
#define W 128
#define NS 120          // 11*11 - 1 shifts
#define HW (H*W)
#define STRIPS 8
#define SH 16           // rows per strip (match kernel)
#define DROWS 26        // SH + 10 padded rows
#define DINW 8

typedef unsigned int u32;
typedef unsigned long long u64;
typedef float f32x4 __attribute__((ext_vector_type(4)));
typedef short bf16x8 __attribute__((ext_vector_type(8)));

// ---------------- kernel 1: per-(b,strip) bitplane popcount match ----------------
__global__ __launch_bounds__(256) void match_strip(
    const int* __restrict__ demo_in, const int* __restrict__ demo_out,
    const float* __restrict__ clw, float* __restrict__ mpart)
{
    __shared__ u32 din_p[COLORS][DROWS][DINW];
    __shared__ u32 dout_p[COLORS][SH][4];
    __shared__ float wexp[COLORS];
    __shared__ float pp[128];

    int t = threadIdx.x;
    int strip = blockIdx.x;
    int b = blockIdx.y;
    int wave = t >> 6, lane = t & 63;

    if (t < COLORS) wexp[t] = __expf(clw[t]);

    const int* di = demo_in  + b * HW;
    const int* dd = demo_out + b * HW;
    int y0 = strip * SH;

    for (int r = wave; r < DROWS; r += 4) {
        int gy = y0 - 5 + r;
        bool ok = (gy >= 0 && gy < H);
        int v0 = 0, v1 = 0;
        if (ok) { v0 = di[gy * W + lane]; v1 = di[gy * W + 64 + lane]; }
        #pragma unroll
        for (int c = 0; c < COLORS; c++) {
            u64 h0 = __ballot(v0 == c);
            u64 h1 = __ballot(v1 == c);
            u64 P0, P1, P2;
            if (!ok) {
                P0 = (c == 0) ? ~0ull : 0ull;
                P1 = P0;
                P2 = (c == 0) ? 0x3FFull : 0ull;
            } else {
                u64 lm = (c == 0) ? 0x1Full  : 0ull;
                u64 rm = (c == 0) ? 0x3E0ull : 0ull;
                P0 = (h0 << 5) | lm;
                P1 = (h0 >> 59) | (h1 << 5);
                P2 = (h1 >> 59) | rm;
            }
            if (lane == 0) {
                u32* w = &din_p[c][r][0];
                w[0] = (u32)P0; w[1] = (u32)(P0 >> 32);
                w[2] = (u32)P1; w[3] = (u32)(P1 >> 32);
                w[4] = (u32)P2; w[5] = 0; w[6] = 0; w[7] = 0;
            }
        }
    }
    for (int r = wave; r < SH; r += 4) {
        int gy = y0 + r;
        int v0 = dd[gy * W + lane], v1 = dd[gy * W + 64 + lane];
        #pragma unroll
        for (int c = 0; c < COLORS; c++) {
            u64 h0 = __ballot(v0 == c);
            u64 h1 = __ballot(v1 == c);
            if (lane == 0) {
                u32* w = &dout_p[c][r][0];
                w[0] = (u32)h0; w[1] = (u32)(h0 >> 32);
                w[2] = (u32)h1; w[3] = (u32)(h1 >> 32);
            }
        }
    }
    __syncthreads();

    int s  = t & 127;
    int yh = t >> 7;
    float acc = 0.f;
    if (s < NS) {
        int lin = s + (s >= 60);
        int dy = lin / 11 - 5, dx = lin % 11 - 5;
        int k = 5 - dx;
        for (int c = 0; c < COLORS; c++) {
            int cnt = 0;
            #pragma unroll
            for (int yy = 0; yy < 8; yy++) {
                int y = yh * 8 + yy;
                int r = y - dy + 5;
                const u32* dr   = &din_p[c][r][0];
                const u32* orow = &dout_p[c][y][0];
                u32 s0 = __builtin_amdgcn_alignbit(dr[1], dr[0], k);
                u32 s1 = __builtin_amdgcn_alignbit(dr[2], dr[1], k);
                u32 s2 = __builtin_amdgcn_alignbit(dr[3], dr[2], k);
                u32 s3 = __builtin_amdgcn_alignbit(dr[4], dr[3], k);
                cnt += __popc(s0 & orow[0]) + __popc(s1 & orow[1])
                     + __popc(s2 & orow[2]) + __popc(s3 & orow[3]);
            }
            acc += wexp[c] * (float)cnt;
        }
    }
    if (yh == 1) pp[s] = acc;
    __syncthreads();
    if (yh == 0 && s < NS)
        mpart[(b * NS + s) * STRIPS + strip] = acc + pp[s];
}

// -------- kernel 2: fused softmax + A-fragments + MFMA accumulation --------
// Block (ytile, b): 4 output rows. Phase B (softmax from mpart) is redundant
// per block (~1-2 us, L2-resident reads); phase C = round-4 proven MFMA body.
__global__ __launch_bounds__(256) void accum_fused(
    const int* __restrict__ query_in, const float* __restrict__ mpart,
    const float* __restrict__ logit_scale, float* __restrict__ out)
{
    __shared__ __align__(16) int qs[14][144];     // padded query rows
    __shared__ float sm[NS];                      // scores -> attention
    __shared__ unsigned short abf[128];           // bf16 att by lin; 60,121..127 = 0

    int t  = threadIdx.x;
    int y0 = blockIdx.x * 4;
    int b  = blockIdx.y;
    const int* q = query_in + b * HW;

    // ---- issue query staging loads early (consumed last) ----
    int vstage[8];
    #pragma unroll
    for (int i = 0; i < 8; i++) {
        int idx = t + i * 256;
        int r = idx / 144;
        int p = idx - r * 144;
        int gy = y0 - 5 + r;
        bool ok = (idx < 2016) & (gy >= 0) & (gy < H) & (p >= 5) & (p < 133);
        int cy = gy < 0 ? 0 : (gy > 127 ? 127 : gy);
        int cx = p < 5 ? 0 : (p > 132 ? 127 : p - 5);
        int ld = q[cy * W + cx];
        vstage[i] = ok ? ld : 0;
    }

    // ---- Phase B: strip reduction + softmax + bf16 attention table ----
    float scale = fminf(__expf(logit_scale[0]), 100.0f) * (1.0f / 128.0f);
    if (t < NS) {
        const float* mp = mpart + (t + b * NS) * STRIPS;
        float4 v0 = *reinterpret_cast<const float4*>(mp);
        float4 v1 = *reinterpret_cast<const float4*>(mp + 4);
        sm[t] = (v0.x + v0.y + v0.z + v0.w + v1.x + v1.y + v1.z + v1.w) * scale;
    }
    __syncthreads();
    if (t < 64) {
        float s0 = sm[t];
        float s1 = (t + 64 < NS) ? sm[t + 64] : -INFINITY;
        float m = fmaxf(s0, s1);
        for (int off = 32; off > 0; off >>= 1) m = fmaxf(m, __shfl_xor(m, off, 64));
        float e0 = __expf(s0 - m);
        float e1 = (t + 64 < NS) ? __expf(s1 - m) : 0.f;
        float sum = e0 + e1;
        for (int off = 32; off > 0; off >>= 1) sum += __shfl_xor(sum, off, 64);
        float inv = 1.0f / sum;
        sm[t] = e0 * inv;
        if (t + 64 < NS) sm[t + 64] = e1 * inv;
    }
    __syncthreads();
    if (t < 128) {
        unsigned short v = 0;
        if (t < 121 && t != 60) {
            int si = t - (t > 60);
            __hip_bfloat16 hb = __float2bfloat16(sm[si]);
            v = *reinterpret_cast<unsigned short*>(&hb);
        }
        abf[t] = v;
    }

    // ---- write staged query rows to LDS ----
    #pragma unroll
    for (int i = 0; i < 8; i++) {
        int idx = t + i * 256;
        if (idx < 2016) ((int*)qs)[idx] = vstage[i];
    }
    __syncthreads();

    // ---- per-lane A fragments: A[m][k=(st,cc)] = att(dy=5-st, dx=m+5-cc) ----
    int lane = t & 63, wv = t >> 6;
    int mrow = lane & 15, g8 = (lane >> 4) * 8;
    uint4 afr[11];
    #pragma unroll
    for (int st = 0; st < 11; st++) {
        u32 wq[4];
        #pragma unroll
        for (int p = 0; p < 4; p++) {
            int j0 = mrow + 10 - (g8 + p * 2);   // dx+5 for hh=0
            int j1 = j0 - 1;                     // hh=1
            int i0 = (j0 >= 0 && j0 <= 10) ? (10 - st) * 11 + j0 : 121;
            int i1 = (j1 >= 0 && j1 <= 10) ? (10 - st) * 11 + j1 : 121;
            wq[p] = (u32)abf[i0] | ((u32)abf[i1] << 16);
        }
        afr[st] = make_uint4(wq[0], wq[1], wq[2], wq[3]);
    }

    // ---- Phase C: MFMA accumulation (round-4 proven body) ----
    int c = lane & 15, g = lane >> 4;

    #pragma unroll
    for (int ti = 0; ti < 2; ti++) {
        int x0 = wv * 32 + ti * 16;

        uint4 bf[14];
        #pragma unroll
        for (int r = 0; r < 14; r++) {
            uint4 qa = *reinterpret_cast<const uint4*>(&qs[r][x0 + 8 * g]);
            uint4 qb = *reinterpret_cast<const uint4*>(&qs[r][x0 + 8 * g + 4]);
            u32 b0 = ((int)qa.x == c ? 0x3F80u : 0u) | ((int)qa.y == c ? 0x3F800000u : 0u);
            u32 b1 = ((int)qa.z == c ? 0x3F80u : 0u) | ((int)qa.w == c ? 0x3F800000u : 0u);
            u32 b2 = ((int)qb.x == c ? 0x3F80u : 0u) | ((int)qb.y == c ? 0x3F800000u : 0u);
            u32 b3 = ((int)qb.z == c ? 0x3F80u : 0u) | ((int)qb.w == c ? 0x3F800000u : 0u);
            bf[r] = make_uint4(b0, b1, b2, b3);
        }

        f32x4 acc[4];
        #pragma unroll
        for (int j = 0; j < 4; j++) acc[j] = (f32x4){0.f, 0.f, 0.f, 0.f};

        #pragma unroll
        for (int st = 0; st < 11; st++) {
            #pragma unroll
            for (int j = 0; j < 4; j++) {
                union { uint4 u; bf16x8 v; } A, B;
                A.u = afr[st];
                B.u = bf[st + j];
                acc[j] = __builtin_amdgcn_mfma_f32_16x16x32_bf16(A.v, B.v, acc[j], 0, 0, 0);
            }
        }

        if (c < COLORS) {
            #pragma unroll
            for (int j = 0; j < 4; j++) {
                float* ob = out + (((size_t)b * COLORS + c) * H + (y0 + j)) * W + x0 + 4 * g;
                float4 rr;
                rr.x = __logf(fmaxf(acc[j][0], 1e-6f));
                rr.y = __logf(fmaxf(acc[j][1], 1e-6f));
                rr.z = __logf(fmaxf(acc[j][2], 1e-6f));
                rr.w = __logf(fmaxf(acc[j][3], 1e-6f));
                *reinterpret_cast<float4*>(ob) = rr;
            }
        }
    }
}

// ----------------------- legacy fallback (tiny ws) -----------------------
__global__ __launch_bounds__(256) void match_kernel(
    const int* __restrict__ demo_in, const int* __restrict__ demo_out,
    const float* __restrict__ clw, float* __restrict__ match)
{
    int blk = blockIdx.x;
    int b = blk / NS;
    int s = blk % NS;
    int lin = s + (s >= 60 ? 1 : 0);
    int dy = lin / 11 - 5, dx = lin % 11 - 5;

    __shared__ float wexp[COLORS];
    int tid = threadIdx.x;
    if (tid < COLORS) wexp[tid] = expf(clw[tid]);
    __syncthreads();

    const int* __restrict__ din  = demo_in  + b * HW;
    const int* __restrict__ dout = demo_out + b * HW;

    float partial = 0.f;
    for (int i = tid; i < HW; i += 256) {
        int yy = i >> 7, xx = i & 127;
        int co = dout[i];
        int sy = yy - dy, sx = xx - dx;
        int v = 0;
        if (sy >= 0 && sy < H && sx >= 0 && sx < W) v = din[sy * W + sx];
        if (v == co) partial += wexp[co];
    }
    for (int off = 32; off > 0; off >>= 1) partial += __shfl_down(partial, off, 64);
    __shared__ float wsum[4];
    if ((tid & 63) == 0) wsum[tid >> 6] = partial;
    __syncthreads();
    if (tid == 0) match[blk] = wsum[0] + wsum[1] + wsum[2] + wsum[3];
}

__global__ __launch_bounds__(64) void softmax_kernel(
    const float* __restrict__ match, const float* __restrict__ logit_scale,
    float* __restrict__ attention)
{
    int b = blockIdx.x;
    int lane = threadIdx.x;
    float scale = fminf(expf(logit_scale[0]), 100.0f) / sqrtf((float)HW);
    int i0 = lane, i1 = lane + 64;
    float s0 = match[b * NS + i0] * scale;
    float s1 = (i1 < NS) ? match[b * NS + i1] * scale : -INFINITY;
    float m = fmaxf(s0, s1);
    for (int off = 32; off > 0; off >>= 1) m = fmaxf(m, __shfl_xor(m, off, 64));
    float e0 = expf(s0 - m);
    float e1 = (i1 < NS) ? expf(s1 - m) : 0.f;
    float sum = e0 + e1;
    for (int off = 32; off > 0; off >>= 1) sum += __shfl_xor(sum, off, 64);
    float inv = 1.0f / sum;
    attention[b * NS + i0] = e0 * inv;
    if (i1 < NS) attention[b * NS + i1] = e1 * inv;
}

__global__ __launch_bounds__(128) void accum_kernel(
    const int* __restrict__ query_in, const float* __restrict__ attention,
    float* __restrict__ out)
{
    int blk = blockIdx.x;
    int b = blk >> 7;
    int y = blk & 127;
    int x = threadIdx.x;

    __shared__ float att[NS];
    if (threadIdx.x < NS) att[threadIdx.x] = attention[b * NS + threadIdx.x];
    __syncthreads();

    const int* __restrict__ q = query_in + b * HW;
    float acc[COLORS];
    #pragma unroll
    for (int c = 0; c < COLORS; c++) acc[c] = 0.f;

    #pragma unroll 4
    for (int s = 0; s < NS; s++) {
        int lin = s + (s >= 60 ? 1 : 0);
        int dy = lin / 11 - 5, dx = lin % 11 - 5;
        int sy = y - dy, sx = x - dx;
        int v = 0;
        if (sy >= 0 && sy < H && sx >= 0 && sx < W) v = q[sy * W + sx];
        float a = att[s];
        #pragma unroll
        for (int c = 0; c < COLORS; c++) acc[c] += (v == c) ? a : 0.f;
    }
    float* __restrict__ ob = out + (size_t)b * COLORS * HW + y * W + x;
    #pragma unroll
    for (int c = 0; c < COLORS; c++) ob[c * HW] = __logf(fmaxf(acc[c], 1e-6f));
}

extern "C" void kernel_launch(void* const* d_in, const int* in_sizes, int n_in,
                              void* d_out, int out_size, void* d_ws, size_t ws_size,
                              hipStream_t stream) {
    const int*   demo_in     = (const int*)d_in[0];
    const int*   demo_out    = (const int*)d_in[1];
    const int*   query_in    = (const int*)d_in[2];
    const float* clw         = (const float*)d_in[3];
    const float* logit_scale = (const float*)d_in[4];
    float* out = (float*)d_out;

    size_t needed = (size_t)NB * NS * STRIPS * sizeof(float);   // 122880 B

    if (ws_size >= needed) {
        float* mpart = (float*)d_ws;
        match_strip<<<dim3(STRIPS, NB), 256, 0, stream>>>(demo_in, demo_out, clw, mpart);
        accum_fused<<<dim3(H / 4, NB), 256, 0, stream>>>(query_in, mpart, logit_scale, out);
    } else {
        float* match = (float*)d_ws;
        float* att   = match + NB * NS;
        match_kernel<<<NB * NS, 256, 0, stream>>>(demo_in, demo_out, clw, match);
        softmax_kernel<<<NB, 64, 0, stream>>>(match, logit_scale, att);
        accum_kernel<<<NB * H, 128, 0, stream>>>(query_in, att, out);
    }
}

// Round 7
// 29.817 us; speedup vs baseline: 5.1070x; 1.1855x over previous
//
#include <hip/hip_runtime.h>
#include <hip/hip_bf16.h>
#include <math.h>

#define COLORS 10
#define NB 32
#define H 128
#define W 128
#define NS 120          // 11*11 - 1 shifts
#define HW (H*W)
#define STRIPS 8
#define SH 16           // rows per strip (match kernel)
#define DROWS 26        // SH + 10 padded rows
#define DINW 8

typedef unsigned char u8;
typedef unsigned int u32;
typedef unsigned long long u64;
typedef float f32x4 __attribute__((ext_vector_type(4)));
typedef short bf16x8 __attribute__((ext_vector_type(8)));

// ---------------- kernel 1: per-(b,strip) bitplane popcount match ----------------
// 512 threads: t = s*4 + q, each thread covers 4 rows; 8 waves/block.
__global__ __launch_bounds__(512) void match_strip(
    const int* __restrict__ demo_in, const int* __restrict__ demo_out,
    const float* __restrict__ clw, float* __restrict__ mpart)
{
    __shared__ u32 din_p[COLORS][DROWS][DINW];
    __shared__ u32 dout_p[COLORS][SH][4];
    __shared__ float wexp[COLORS];

    int t = threadIdx.x;
    int strip = blockIdx.x;
    int b = blockIdx.y;
    int wave = t >> 6, lane = t & 63;

    if (t < COLORS) wexp[t] = __expf(clw[t]);

    const int* di = demo_in  + b * HW;
    const int* dd = demo_out + b * HW;
    int y0 = strip * SH;

    for (int r = wave; r < DROWS; r += 8) {
        int gy = y0 - 5 + r;
        bool ok = (gy >= 0 && gy < H);
        int v0 = 0, v1 = 0;
        if (ok) { v0 = di[gy * W + lane]; v1 = di[gy * W + 64 + lane]; }
        #pragma unroll
        for (int c = 0; c < COLORS; c++) {
            u64 h0 = __ballot(v0 == c);
            u64 h1 = __ballot(v1 == c);
            u64 P0, P1, P2;
            if (!ok) {
                P0 = (c == 0) ? ~0ull : 0ull;
                P1 = P0;
                P2 = (c == 0) ? 0x3FFull : 0ull;
            } else {
                u64 lm = (c == 0) ? 0x1Full  : 0ull;
                u64 rm = (c == 0) ? 0x3E0ull : 0ull;
                P0 = (h0 << 5) | lm;
                P1 = (h0 >> 59) | (h1 << 5);
                P2 = (h1 >> 59) | rm;
            }
            if (lane == 0) {
                u32* w = &din_p[c][r][0];
                w[0] = (u32)P0; w[1] = (u32)(P0 >> 32);
                w[2] = (u32)P1; w[3] = (u32)(P1 >> 32);
                w[4] = (u32)P2; w[5] = 0; w[6] = 0; w[7] = 0;
            }
        }
    }
    for (int r = wave; r < SH; r += 8) {
        int gy = y0 + r;
        int v0 = dd[gy * W + lane], v1 = dd[gy * W + 64 + lane];
        #pragma unroll
        for (int c = 0; c < COLORS; c++) {
            u64 h0 = __ballot(v0 == c);
            u64 h1 = __ballot(v1 == c);
            if (lane == 0) {
                u32* w = &dout_p[c][r][0];
                w[0] = (u32)h0; w[1] = (u32)(h0 >> 32);
                w[2] = (u32)h1; w[3] = (u32)(h1 >> 32);
            }
        }
    }
    __syncthreads();

    int s = t >> 2, q = t & 3;
    float acc = 0.f;
    if (t < 4 * NS) {
        int lin = s + (s >= 60);
        int dy = lin / 11 - 5, dx = lin % 11 - 5;
        int k = 5 - dx;
        for (int c = 0; c < COLORS; c++) {
            int cnt = 0;
            #pragma unroll
            for (int yy = 0; yy < 4; yy++) {
                int y = q * 4 + yy;
                int r = y - dy + 5;                 // 0..25
                const u32* dr   = &din_p[c][r][0];
                const u32* orow = &dout_p[c][y][0];
                u32 s0 = __builtin_amdgcn_alignbit(dr[1], dr[0], k);
                u32 s1 = __builtin_amdgcn_alignbit(dr[2], dr[1], k);
                u32 s2 = __builtin_amdgcn_alignbit(dr[3], dr[2], k);
                u32 s3 = __builtin_amdgcn_alignbit(dr[4], dr[3], k);
                cnt += __popc(s0 & orow[0]) + __popc(s1 & orow[1])
                     + __popc(s2 & orow[2]) + __popc(s3 & orow[3]);
            }
            acc += wexp[c] * (float)cnt;
        }
    }
    acc += __shfl_down(acc, 1, 64);
    acc += __shfl_down(acc, 2, 64);
    if (q == 0 && t < 4 * NS)
        mpart[(b * NS + s) * STRIPS + strip] = acc;
}

// -------- kernel 2: fused softmax + shared A-table + MFMA accumulation --------
// 512 threads, block (ytile,b) covers 8 output rows. qs stored as BYTES
// (1 ds_read_b64 per B-fragment); A-fragment table built cooperatively in LDS.
#define AR 18            // staged padded rows
__global__ __launch_bounds__(512) void accum_fused(
    const int* __restrict__ query_in, const float* __restrict__ mpart,
    const float* __restrict__ logit_scale, float* __restrict__ out)
{
    __shared__ u8  qs[AR][144];                    // 2592 B, byte colors
    __shared__ float sm[NS];
    __shared__ unsigned short abf[128];            // bf16 att by lin; 60,121..127 = 0
    __shared__ __align__(16) u32 Agl[11][64][4];   // A-fragments, 11264 B

    int t  = threadIdx.x;
    int y0 = blockIdx.x * 8;
    int b  = blockIdx.y;
    const int* q = query_in + b * HW;

    // ---- staging: pack 4 clamped pixels -> 1 u32 (issue all loads early) ----
    u32 pk0 = 0, pk1 = 0;
    {
        int g = t;                                  // bytes 4g..4g+3 (< 2048 < 2592)
        #pragma unroll
        for (int e = 0; e < 4; e++) {
            int idx = g * 4 + e;
            int r = idx / 144, p = idx - r * 144;
            int gy = y0 - 5 + r;
            bool ok = (gy >= 0) & (gy < H) & (p >= 5) & (p < 133);
            int cy = gy < 0 ? 0 : (gy > 127 ? 127 : gy);
            int cx = p < 5 ? 0 : (p > 132 ? 127 : p - 5);
            int v = q[cy * W + cx];
            pk0 |= (u32)(ok ? v : 0) << (8 * e);
        }
    }
    if (t < 648 - 512) {
        int g = t + 512;
        #pragma unroll
        for (int e = 0; e < 4; e++) {
            int idx = g * 4 + e;
            int r = idx / 144, p = idx - r * 144;
            int gy = y0 - 5 + r;
            bool ok = (gy >= 0) & (gy < H) & (p >= 5) & (p < 133);
            int cy = gy < 0 ? 0 : (gy > 127 ? 127 : gy);
            int cx = p < 5 ? 0 : (p > 132 ? 127 : p - 5);
            int v = q[cy * W + cx];
            pk1 |= (u32)(ok ? v : 0) << (8 * e);
        }
    }

    // ---- phase B part 1: strip reduction ----
    float scale = fminf(__expf(logit_scale[0]), 100.0f) * (1.0f / 128.0f);
    if (t < NS) {
        const float* mp = mpart + (t + b * NS) * STRIPS;
        float4 v0 = *reinterpret_cast<const float4*>(mp);
        float4 v1 = *reinterpret_cast<const float4*>(mp + 4);
        sm[t] = (v0.x + v0.y + v0.z + v0.w + v1.x + v1.y + v1.z + v1.w) * scale;
    }

    ((u32*)qs)[t] = pk0;
    if (t < 648 - 512) ((u32*)qs)[t + 512] = pk1;
    __syncthreads();

    // ---- softmax (wave 0) ----
    if (t < 64) {
        float s0 = sm[t];
        float s1 = (t + 64 < NS) ? sm[t + 64] : -INFINITY;
        float m = fmaxf(s0, s1);
        for (int off = 32; off > 0; off >>= 1) m = fmaxf(m, __shfl_xor(m, off, 64));
        float e0 = __expf(s0 - m);
        float e1 = (t + 64 < NS) ? __expf(s1 - m) : 0.f;
        float sum = e0 + e1;
        for (int off = 32; off > 0; off >>= 1) sum += __shfl_xor(sum, off, 64);
        float inv = 1.0f / sum;
        sm[t] = e0 * inv;
        if (t + 64 < NS) sm[t + 64] = e1 * inv;
    }
    __syncthreads();
    if (t < 128) {
        unsigned short v = 0;
        if (t < 121 && t != 60) {
            int si = t - (t > 60);
            __hip_bfloat16 hb = __float2bfloat16(sm[si]);
            v = *reinterpret_cast<unsigned short*>(&hb);
        }
        abf[t] = v;
    }
    __syncthreads();

    // ---- cooperative A-fragment table: 704 entries over 512 threads ----
    {
        int e = t;
        int st = e >> 6, l = e & 63;
        int mrow = l & 15, g8 = (l >> 4) * 8;
        #pragma unroll
        for (int p = 0; p < 4; p++) {
            int j0 = mrow + 10 - (g8 + p * 2);
            int j1 = j0 - 1;
            int i0 = (j0 >= 0 && j0 <= 10) ? (10 - st) * 11 + j0 : 121;
            int i1 = (j1 >= 0 && j1 <= 10) ? (10 - st) * 11 + j1 : 121;
            Agl[st][l][p] = (u32)abf[i0] | ((u32)abf[i1] << 16);
        }
    }
    if (t < 704 - 512) {
        int e = t + 512;
        int st = e >> 6, l = e & 63;
        int mrow = l & 15, g8 = (l >> 4) * 8;
        #pragma unroll
        for (int p = 0; p < 4; p++) {
            int j0 = mrow + 10 - (g8 + p * 2);
            int j1 = j0 - 1;
            int i0 = (j0 >= 0 && j0 <= 10) ? (10 - st) * 11 + j0 : 121;
            int i1 = (j1 >= 0 && j1 <= 10) ? (10 - st) * 11 + j1 : 121;
            Agl[st][l][p] = (u32)abf[i0] | ((u32)abf[i1] << 16);
        }
    }
    __syncthreads();

    // ---- per-wave fragments & MFMA ----
    int lane = t & 63, w = t >> 6;
    uint4 afr[11];
    #pragma unroll
    for (int st = 0; st < 11; st++)
        afr[st] = *reinterpret_cast<const uint4*>(&Agl[st][lane][0]);

    int jb = (w >> 2) * 4;      // row half: 0 or 4
    int xq = w & 3;             // column quarter
    int c = lane & 15, g = lane >> 4;

    #pragma unroll
    for (int ti = 0; ti < 2; ti++) {
        int x0 = xq * 32 + ti * 16;

        uint4 bf[14];
        #pragma unroll
        for (int r = 0; r < 14; r++) {
            u64 eight = *reinterpret_cast<const u64*>(&qs[jb + r][x0 + 8 * g]);
            u32 lo = (u32)eight, hi = (u32)(eight >> 32);
            u32 b0 = ((int)(lo & 255) == c ? 0x3F80u : 0u)
                   | ((int)((lo >> 8)  & 255) == c ? 0x3F800000u : 0u);
            u32 b1 = ((int)((lo >> 16) & 255) == c ? 0x3F80u : 0u)
                   | ((int)((lo >> 24) & 255) == c ? 0x3F800000u : 0u);
            u32 b2 = ((int)(hi & 255) == c ? 0x3F80u : 0u)
                   | ((int)((hi >> 8)  & 255) == c ? 0x3F800000u : 0u);
            u32 b3 = ((int)((hi >> 16) & 255) == c ? 0x3F80u : 0u)
                   | ((int)((hi >> 24) & 255) == c ? 0x3F800000u : 0u);
            bf[r] = make_uint4(b0, b1, b2, b3);
        }

        f32x4 acc[4];
        #pragma unroll
        for (int j = 0; j < 4; j++) acc[j] = (f32x4){0.f, 0.f, 0.f, 0.f};

        #pragma unroll
        for (int st = 0; st < 11; st++) {
            #pragma unroll
            for (int j = 0; j < 4; j++) {
                union { uint4 u; bf16x8 v; } A, B;
                A.u = afr[st];
                B.u = bf[st + j];
                acc[j] = __builtin_amdgcn_mfma_f32_16x16x32_bf16(A.v, B.v, acc[j], 0, 0, 0);
            }
        }

        if (c < COLORS) {
            #pragma unroll
            for (int j = 0; j < 4; j++) {
                float* ob = out + (((size_t)b * COLORS + c) * H + (y0 + jb + j)) * W + x0 + 4 * g;
                float4 rr;
                rr.x = __logf(fmaxf(acc[j][0], 1e-6f));
                rr.y = __logf(fmaxf(acc[j][1], 1e-6f));
                rr.z = __logf(fmaxf(acc[j][2], 1e-6f));
                rr.w = __logf(fmaxf(acc[j][3], 1e-6f));
                *reinterpret_cast<float4*>(ob) = rr;
            }
        }
    }
}

// ----------------------- legacy fallback (tiny ws) -----------------------
__global__ __launch_bounds__(256) void match_kernel(
    const int* __restrict__ demo_in, const int* __restrict__ demo_out,
    const float* __restrict__ clw, float* __restrict__ match)
{
    int blk = blockIdx.x;
    int b = blk / NS;
    int s = blk % NS;
    int lin = s + (s >= 60 ? 1 : 0);
    int dy = lin / 11 - 5, dx = lin % 11 - 5;

    __shared__ float wexp[COLORS];
    int tid = threadIdx.x;
    if (tid < COLORS) wexp[tid] = expf(clw[tid]);
    __syncthreads();

    const int* __restrict__ din  = demo_in  + b * HW;
    const int* __restrict__ dout = demo_out + b * HW;

    float partial = 0.f;
    for (int i = tid; i < HW; i += 256) {
        int yy = i >> 7, xx = i & 127;
        int co = dout[i];
        int sy = yy - dy, sx = xx - dx;
        int v = 0;
        if (sy >= 0 && sy < H && sx >= 0 && sx < W) v = din[sy * W + sx];
        if (v == co) partial += wexp[co];
    }
    for (int off = 32; off > 0; off >>= 1) partial += __shfl_down(partial, off, 64);
    __shared__ float wsum[4];
    if ((tid & 63) == 0) wsum[tid >> 6] = partial;
    __syncthreads();
    if (tid == 0) match[blk] = wsum[0] + wsum[1] + wsum[2] + wsum[3];
}

__global__ __launch_bounds__(64) void softmax_kernel(
    const float* __restrict__ match, const float* __restrict__ logit_scale,
    float* __restrict__ attention)
{
    int b = blockIdx.x;
    int lane = threadIdx.x;
    float scale = fminf(expf(logit_scale[0]), 100.0f) / sqrtf((float)HW);
    int i0 = lane, i1 = lane + 64;
    float s0 = match[b * NS + i0] * scale;
    float s1 = (i1 < NS) ? match[b * NS + i1] * scale : -INFINITY;
    float m = fmaxf(s0, s1);
    for (int off = 32; off > 0; off >>= 1) m = fmaxf(m, __shfl_xor(m, off, 64));
    float e0 = expf(s0 - m);
    float e1 = (i1 < NS) ? expf(s1 - m) : 0.f;
    float sum = e0 + e1;
    for (int off = 32; off > 0; off >>= 1) sum += __shfl_xor(sum, off, 64);
    float inv = 1.0f / sum;
    attention[b * NS + i0] = e0 * inv;
    if (i1 < NS) attention[b * NS + i1] = e1 * inv;
}

__global__ __launch_bounds__(128) void accum_kernel(
    const int* __restrict__ query_in, const float* __restrict__ attention,
    float* __restrict__ out)
{
    int blk = blockIdx.x;
    int b = blk >> 7;
    int y = blk & 127;
    int x = threadIdx.x;

    __shared__ float att[NS];
    if (threadIdx.x < NS) att[threadIdx.x] = attention[b * NS + threadIdx.x];
    __syncthreads();

    const int* __restrict__ q = query_in + b * HW;
    float acc[COLORS];
    #pragma unroll
    for (int c = 0; c < COLORS; c++) acc[c] = 0.f;

    #pragma unroll 4
    for (int s = 0; s < NS; s++) {
        int lin = s + (s >= 60 ? 1 : 0);
        int dy = lin / 11 - 5, dx = lin % 11 - 5;
        int sy = y - dy, sx = x - dx;
        int v = 0;
        if (sy >= 0 && sy < H && sx >= 0 && sx < W) v = q[sy * W + sx];
        float a = att[s];
        #pragma unroll
        for (int c = 0; c < COLORS; c++) acc[c] += (v == c) ? a : 0.f;
    }
    float* __restrict__ ob = out + (size_t)b * COLORS * HW + y * W + x;
    #pragma unroll
    for (int c = 0; c < COLORS; c++) ob[c * HW] = __logf(fmaxf(acc[c], 1e-6f));
}

extern "C" void kernel_launch(void* const* d_in, const int* in_sizes, int n_in,
                              void* d_out, int out_size, void* d_ws, size_t ws_size,
                              hipStream_t stream) {
    const int*   demo_in     = (const int*)d_in[0];
    const int*   demo_out    = (const int*)d_in[1];
    const int*   query_in    = (const int*)d_in[2];
    const float* clw         = (const float*)d_in[3];
    const float* logit_scale = (const float*)d_in[4];
    float* out = (float*)d_out;

    size_t needed = (size_t)NB * NS * STRIPS * sizeof(float);   // 122880 B

    if (ws_size >= needed) {
        float* mpart = (float*)d_ws;
        match_strip<<<dim3(STRIPS, NB), 512, 0, stream>>>(demo_in, demo_out, clw, mpart);
        accum_fused<<<dim3(H / 8, NB), 512, 0, stream>>>(query_in, mpart, logit_scale, out);
    } else {
        float* match = (float*)d_ws;
        float* att   = match + NB * NS;
        match_kernel<<<NB * NS, 256, 0, stream>>>(demo_in, demo_out, clw, match);
        softmax_kernel<<<NB, 64, 0, stream>>>(match, logit_scale, att);
        accum_kernel<<<NB * H, 128, 0, stream>>>(query_in, att, out);
    }
}

// Round 8
// 28.645 us; speedup vs baseline: 5.3159x; 1.0409x over previous
//
#include <hip/hip_runtime.h>
#include <hip/hip_bf16.h>
#include <math.h>

#define COLORS 10
#define NB 32
#define H 128
#define W 128
#define NS 120          // 11*11 - 1 shifts
#define HW (H*W)
#define STRIPS 8
#define SH 16           // rows per strip (match kernel)
#define DROWS 26        // SH + 10 padded rows
#define DINW 12         // padded D row stride in u32 (48B: 16B-aligned, bank-staggered)

typedef unsigned char u8;
typedef unsigned int u32;
typedef unsigned long long u64;
typedef float f32x4 __attribute__((ext_vector_type(4)));
typedef short bf16x8 __attribute__((ext_vector_type(8)));

// ---------------- kernel 1: per-(b,strip) bitplane popcount match ----------------
// 512 threads: t = s*4 + q, each thread covers 4 rows; 8 waves/block.
__global__ __launch_bounds__(512) void match_strip(
    const int* __restrict__ demo_in, const int* __restrict__ demo_out,
    const float* __restrict__ clw, float* __restrict__ mpart)
{
    __shared__ __align__(16) u32 din_p[COLORS][DROWS][DINW];   // 12480 B
    __shared__ __align__(16) u32 dout_p[COLORS][SH][4];        // 2560 B
    __shared__ float wexp[COLORS];

    int t = threadIdx.x;
    int strip = blockIdx.x;
    int b = blockIdx.y;
    int wave = t >> 6, lane = t & 63;

    if (t < COLORS) wexp[t] = __expf(clw[t]);

    const int* di = demo_in  + b * HW;
    const int* dd = demo_out + b * HW;
    int y0 = strip * SH;

    for (int r = wave; r < DROWS; r += 8) {
        int gy = y0 - 5 + r;
        bool ok = (gy >= 0 && gy < H);
        int v0 = 0, v1 = 0;
        if (ok) { v0 = di[gy * W + lane]; v1 = di[gy * W + 64 + lane]; }
        #pragma unroll
        for (int c = 0; c < COLORS; c++) {
            u64 h0 = __ballot(v0 == c);          // wave-uniform result
            u64 h1 = __ballot(v1 == c);
            u64 P0, P1, P2;
            if (!ok) {
                P0 = (c == 0) ? ~0ull : 0ull;
                P1 = P0;
                P2 = (c == 0) ? 0x3FFull : 0ull;
            } else {
                u64 lm = (c == 0) ? 0x1Full  : 0ull;
                u64 rm = (c == 0) ? 0x3E0ull : 0ull;
                P0 = (h0 << 5) | lm;
                P1 = (h0 >> 59) | (h1 << 5);
                P2 = (h1 >> 59) | rm;
            }
            if (lane == 0) {
                *reinterpret_cast<uint4*>(&din_p[c][r][0]) =
                    make_uint4((u32)P0, (u32)(P0 >> 32), (u32)P1, (u32)(P1 >> 32));
                *reinterpret_cast<uint4*>(&din_p[c][r][4]) =
                    make_uint4((u32)P2, 0u, 0u, 0u);
            }
        }
    }
    for (int r = wave; r < SH; r += 8) {
        int gy = y0 + r;
        int v0 = dd[gy * W + lane], v1 = dd[gy * W + 64 + lane];
        #pragma unroll
        for (int c = 0; c < COLORS; c++) {
            u64 h0 = __ballot(v0 == c);
            u64 h1 = __ballot(v1 == c);
            if (lane == 0)
                *reinterpret_cast<uint4*>(&dout_p[c][r][0]) =
                    make_uint4((u32)h0, (u32)(h0 >> 32), (u32)h1, (u32)(h1 >> 32));
        }
    }
    __syncthreads();

    int s = t >> 2, q = t & 3;
    float acc = 0.f;
    if (t < 4 * NS) {
        int lin = s + (s >= 60);
        int dy = lin / 11 - 5, dx = lin % 11 - 5;
        int k = 5 - dx;
        for (int c = 0; c < COLORS; c++) {
            int cnt = 0;
            #pragma unroll
            for (int yy = 0; yy < 4; yy++) {
                int y = q * 4 + yy;
                int r = y - dy + 5;                 // 0..25
                const u32* dr   = &din_p[c][r][0];
                const u32* orow = &dout_p[c][y][0];
                u32 s0 = __builtin_amdgcn_alignbit(dr[1], dr[0], k);
                u32 s1 = __builtin_amdgcn_alignbit(dr[2], dr[1], k);
                u32 s2 = __builtin_amdgcn_alignbit(dr[3], dr[2], k);
                u32 s3 = __builtin_amdgcn_alignbit(dr[4], dr[3], k);
                cnt += __popc(s0 & orow[0]) + __popc(s1 & orow[1])
                     + __popc(s2 & orow[2]) + __popc(s3 & orow[3]);
            }
            acc += wexp[c] * (float)cnt;
        }
    }
    acc += __shfl_down(acc, 1, 64);
    acc += __shfl_down(acc, 2, 64);
    if (q == 0 && t < 4 * NS)
        mpart[(b * NS + s) * STRIPS + strip] = acc;
}

// -------- kernel 2: fused softmax + shared A-table + MFMA accumulation --------
// 512 threads, block (ytile,b) covers 8 output rows. Wave w owns column slice
// x0=w*16 and BOTH row halves via an 8-row sliding B-window (18 builds/wave).
#define AR 18            // staged padded rows
__global__ __launch_bounds__(512) void accum_fused(
    const int* __restrict__ query_in, const float* __restrict__ mpart,
    const float* __restrict__ logit_scale, float* __restrict__ out)
{
    __shared__ u8  qs[AR][144];                    // 2592 B, byte colors
    __shared__ float sm[NS];
    __shared__ unsigned short abf[128];            // bf16 att by lin; 60,121..127 = 0
    __shared__ __align__(16) u32 Agl[11][64][4];   // A-fragments, 11264 B

    int t  = threadIdx.x;
    int y0 = blockIdx.x * 8;
    int b  = blockIdx.y;
    const int* q = query_in + b * HW;

    // ---- staging: pack 4 clamped pixels -> 1 u32 (issue all loads early) ----
    u32 pk0 = 0, pk1 = 0;
    {
        int g = t;                                  // bytes 4g..4g+3
        #pragma unroll
        for (int e = 0; e < 4; e++) {
            int idx = g * 4 + e;
            int r = idx / 144, p = idx - r * 144;
            int gy = y0 - 5 + r;
            bool ok = (gy >= 0) & (gy < H) & (p >= 5) & (p < 133);
            int cy = gy < 0 ? 0 : (gy > 127 ? 127 : gy);
            int cx = p < 5 ? 0 : (p > 132 ? 127 : p - 5);
            int v = q[cy * W + cx];
            pk0 |= (u32)(ok ? v : 0) << (8 * e);
        }
    }
    if (t < 648 - 512) {
        int g = t + 512;
        #pragma unroll
        for (int e = 0; e < 4; e++) {
            int idx = g * 4 + e;
            int r = idx / 144, p = idx - r * 144;
            int gy = y0 - 5 + r;
            bool ok = (gy >= 0) & (gy < H) & (p >= 5) & (p < 133);
            int cy = gy < 0 ? 0 : (gy > 127 ? 127 : gy);
            int cx = p < 5 ? 0 : (p > 132 ? 127 : p - 5);
            int v = q[cy * W + cx];
            pk1 |= (u32)(ok ? v : 0) << (8 * e);
        }
    }

    // ---- phase B part 1: strip reduction ----
    float scale = fminf(__expf(logit_scale[0]), 100.0f) * (1.0f / 128.0f);
    if (t < NS) {
        const float* mp = mpart + (t + b * NS) * STRIPS;
        float4 v0 = *reinterpret_cast<const float4*>(mp);
        float4 v1 = *reinterpret_cast<const float4*>(mp + 4);
        sm[t] = (v0.x + v0.y + v0.z + v0.w + v1.x + v1.y + v1.z + v1.w) * scale;
    }

    ((u32*)qs)[t] = pk0;
    if (t < 648 - 512) ((u32*)qs)[t + 512] = pk1;
    __syncthreads();

    // ---- softmax (wave 0) ----
    if (t < 64) {
        float s0 = sm[t];
        float s1 = (t + 64 < NS) ? sm[t + 64] : -INFINITY;
        float m = fmaxf(s0, s1);
        for (int off = 32; off > 0; off >>= 1) m = fmaxf(m, __shfl_xor(m, off, 64));
        float e0 = __expf(s0 - m);
        float e1 = (t + 64 < NS) ? __expf(s1 - m) : 0.f;
        float sum = e0 + e1;
        for (int off = 32; off > 0; off >>= 1) sum += __shfl_xor(sum, off, 64);
        float inv = 1.0f / sum;
        sm[t] = e0 * inv;
        if (t + 64 < NS) sm[t + 64] = e1 * inv;
    }
    __syncthreads();
    if (t < 128) {
        unsigned short v = 0;
        if (t < 121 && t != 60) {
            int si = t - (t > 60);
            __hip_bfloat16 hb = __float2bfloat16(sm[si]);
            v = *reinterpret_cast<unsigned short*>(&hb);
        }
        abf[t] = v;
    }
    __syncthreads();

    // ---- cooperative A-fragment table: 704 entries over 512 threads ----
    {
        int e = t;
        int st = e >> 6, l = e & 63;
        int mrow = l & 15, g8 = (l >> 4) * 8;
        #pragma unroll
        for (int p = 0; p < 4; p++) {
            int j0 = mrow + 10 - (g8 + p * 2);
            int j1 = j0 - 1;
            int i0 = (j0 >= 0 && j0 <= 10) ? (10 - st) * 11 + j0 : 121;
            int i1 = (j1 >= 0 && j1 <= 10) ? (10 - st) * 11 + j1 : 121;
            Agl[st][l][p] = (u32)abf[i0] | ((u32)abf[i1] << 16);
        }
    }
    if (t < 704 - 512) {
        int e = t + 512;
        int st = e >> 6, l = e & 63;
        int mrow = l & 15, g8 = (l >> 4) * 8;
        #pragma unroll
        for (int p = 0; p < 4; p++) {
            int j0 = mrow + 10 - (g8 + p * 2);
            int j1 = j0 - 1;
            int i0 = (j0 >= 0 && j0 <= 10) ? (10 - st) * 11 + j0 : 121;
            int i1 = (j1 >= 0 && j1 <= 10) ? (10 - st) * 11 + j1 : 121;
            Agl[st][l][p] = (u32)abf[i0] | ((u32)abf[i1] << 16);
        }
    }
    __syncthreads();

    // ---- per-wave MFMA: column slice x0, 8-row sliding B-window ----
    int lane = t & 63, w = t >> 6;
    int x0 = w * 16;
    int c = lane & 15, g = lane >> 4;

    #define BUILD_B(r) ({                                                        \
        u64 eight = *reinterpret_cast<const u64*>(&qs[(r)][x0 + 8 * g]);         \
        u32 lo = (u32)eight, hi = (u32)(eight >> 32);                            \
        u32 b0 = ((int)(lo & 255) == c ? 0x3F80u : 0u)                           \
               | ((int)((lo >> 8)  & 255) == c ? 0x3F800000u : 0u);              \
        u32 b1 = ((int)((lo >> 16) & 255) == c ? 0x3F80u : 0u)                   \
               | ((int)((lo >> 24) & 255) == c ? 0x3F800000u : 0u);              \
        u32 b2 = ((int)(hi & 255) == c ? 0x3F80u : 0u)                           \
               | ((int)((hi >> 8)  & 255) == c ? 0x3F800000u : 0u);              \
        u32 b3 = ((int)((hi >> 16) & 255) == c ? 0x3F80u : 0u)                   \
               | ((int)((hi >> 24) & 255) == c ? 0x3F800000u : 0u);              \
        make_uint4(b0, b1, b2, b3); })

    uint4 bf[8];
    #pragma unroll
    for (int r = 0; r < 7; r++) bf[r & 7] = BUILD_B(r);

    f32x4 acc0[4], acc1[4];
    #pragma unroll
    for (int j = 0; j < 4; j++) { acc0[j] = (f32x4){0,0,0,0}; acc1[j] = (f32x4){0,0,0,0}; }

    #pragma unroll
    for (int st = 0; st < 11; st++) {
        bf[(st + 7) & 7] = BUILD_B(st + 7);
        uint4 a4 = *reinterpret_cast<const uint4*>(&Agl[st][lane][0]);
        union { uint4 u; bf16x8 v; } A; A.u = a4;
        #pragma unroll
        for (int j = 0; j < 4; j++) {
            union { uint4 u; bf16x8 v; } B0, B1;
            B0.u = bf[(st + j) & 7];
            B1.u = bf[(st + 4 + j) & 7];
            acc0[j] = __builtin_amdgcn_mfma_f32_16x16x32_bf16(A.v, B0.v, acc0[j], 0, 0, 0);
            acc1[j] = __builtin_amdgcn_mfma_f32_16x16x32_bf16(A.v, B1.v, acc1[j], 0, 0, 0);
        }
    }
    #undef BUILD_B

    if (c < COLORS) {
        #pragma unroll
        for (int j = 0; j < 4; j++) {
            float* ob0 = out + (((size_t)b * COLORS + c) * H + (y0 + j)) * W + x0 + 4 * g;
            float4 r0;
            r0.x = __logf(fmaxf(acc0[j][0], 1e-6f));
            r0.y = __logf(fmaxf(acc0[j][1], 1e-6f));
            r0.z = __logf(fmaxf(acc0[j][2], 1e-6f));
            r0.w = __logf(fmaxf(acc0[j][3], 1e-6f));
            *reinterpret_cast<float4*>(ob0) = r0;
            float* ob1 = out + (((size_t)b * COLORS + c) * H + (y0 + 4 + j)) * W + x0 + 4 * g;
            float4 r1;
            r1.x = __logf(fmaxf(acc1[j][0], 1e-6f));
            r1.y = __logf(fmaxf(acc1[j][1], 1e-6f));
            r1.z = __logf(fmaxf(acc1[j][2], 1e-6f));
            r1.w = __logf(fmaxf(acc1[j][3], 1e-6f));
            *reinterpret_cast<float4*>(ob1) = r1;
        }
    }
}

// ----------------------- legacy fallback (tiny ws) -----------------------
__global__ __launch_bounds__(256) void match_kernel(
    const int* __restrict__ demo_in, const int* __restrict__ demo_out,
    const float* __restrict__ clw, float* __restrict__ match)
{
    int blk = blockIdx.x;
    int b = blk / NS;
    int s = blk % NS;
    int lin = s + (s >= 60 ? 1 : 0);
    int dy = lin / 11 - 5, dx = lin % 11 - 5;

    __shared__ float wexp[COLORS];
    int tid = threadIdx.x;
    if (tid < COLORS) wexp[tid] = expf(clw[tid]);
    __syncthreads();

    const int* __restrict__ din  = demo_in  + b * HW;
    const int* __restrict__ dout = demo_out + b * HW;

    float partial = 0.f;
    for (int i = tid; i < HW; i += 256) {
        int yy = i >> 7, xx = i & 127;
        int co = dout[i];
        int sy = yy - dy, sx = xx - dx;
        int v = 0;
        if (sy >= 0 && sy < H && sx >= 0 && sx < W) v = din[sy * W + sx];
        if (v == co) partial += wexp[co];
    }
    for (int off = 32; off > 0; off >>= 1) partial += __shfl_down(partial, off, 64);
    __shared__ float wsum[4];
    if ((tid & 63) == 0) wsum[tid >> 6] = partial;
    __syncthreads();
    if (tid == 0) match[blk] = wsum[0] + wsum[1] + wsum[2] + wsum[3];
}

__global__ __launch_bounds__(64) void softmax_kernel(
    const float* __restrict__ match, const float* __restrict__ logit_scale,
    float* __restrict__ attention)
{
    int b = blockIdx.x;
    int lane = threadIdx.x;
    float scale = fminf(expf(logit_scale[0]), 100.0f) / sqrtf((float)HW);
    int i0 = lane, i1 = lane + 64;
    float s0 = match[b * NS + i0] * scale;
    float s1 = (i1 < NS) ? match[b * NS + i1] * scale : -INFINITY;
    float m = fmaxf(s0, s1);
    for (int off = 32; off > 0; off >>= 1) m = fmaxf(m, __shfl_xor(m, off, 64));
    float e0 = expf(s0 - m);
    float e1 = (i1 < NS) ? expf(s1 - m) : 0.f;
    float sum = e0 + e1;
    for (int off = 32; off > 0; off >>= 1) sum += __shfl_xor(sum, off, 64);
    float inv = 1.0f / sum;
    attention[b * NS + i0] = e0 * inv;
    if (i1 < NS) attention[b * NS + i1] = e1 * inv;
}

__global__ __launch_bounds__(128) void accum_kernel(
    const int* __restrict__ query_in, const float* __restrict__ attention,
    float* __restrict__ out)
{
    int blk = blockIdx.x;
    int b = blk >> 7;
    int y = blk & 127;
    int x = threadIdx.x;

    __shared__ float att[NS];
    if (threadIdx.x < NS) att[threadIdx.x] = attention[b * NS + threadIdx.x];
    __syncthreads();

    const int* __restrict__ q = query_in + b * HW;
    float acc[COLORS];
    #pragma unroll
    for (int c = 0; c < COLORS; c++) acc[c] = 0.f;

    #pragma unroll 4
    for (int s = 0; s < NS; s++) {
        int lin = s + (s >= 60 ? 1 : 0);
        int dy = lin / 11 - 5, dx = lin % 11 - 5;
        int sy = y - dy, sx = x - dx;
        int v = 0;
        if (sy >= 0 && sy < H && sx >= 0 && sx < W) v = q[sy * W + sx];
        float a = att[s];
        #pragma unroll
        for (int c = 0; c < COLORS; c++) acc[c] += (v == c) ? a : 0.f;
    }
    float* __restrict__ ob = out + (size_t)b * COLORS * HW + y * W + x;
    #pragma unroll
    for (int c = 0; c < COLORS; c++) ob[c * HW] = __logf(fmaxf(acc[c], 1e-6f));
}

extern "C" void kernel_launch(void* const* d_in, const int* in_sizes, int n_in,
                              void* d_out, int out_size, void* d_ws, size_t ws_size,
                              hipStream_t stream) {
    const int*   demo_in     = (const int*)d_in[0];
    const int*   demo_out    = (const int*)d_in[1];
    const int*   query_in    = (const int*)d_in[2];
    const float* clw         = (const float*)d_in[3];
    const float* logit_scale = (const float*)d_in[4];
    float* out = (float*)d_out;

    size_t needed = (size_t)NB * NS * STRIPS * sizeof(float);   // 122880 B

    if (ws_size >= needed) {
        float* mpart = (float*)d_ws;
        match_strip<<<dim3(STRIPS, NB), 512, 0, stream>>>(demo_in, demo_out, clw, mpart);
        accum_fused<<<dim3(H / 8, NB), 512, 0, stream>>>(query_in, mpart, logit_scale, out);
    } else {
        float* match = (float*)d_ws;
        float* att   = match + NB * NS;
        match_kernel<<<NB * NS, 256, 0, stream>>>(demo_in, demo_out, clw, match);
        softmax_kernel<<<NB, 64, 0, stream>>>(match, logit_scale, att);
        accum_kernel<<<NB * H, 128, 0, stream>>>(query_in, att, out);
    }
}